// Round 4
// baseline (222.640 us; speedup 1.0000x reference)
//
#include <hip/hip_runtime.h>
#include <math.h>

constexpr int N_ROWS = 1024;
constexpr int DDIM   = 512;
constexpr int C_CLS  = 100000;
constexpr float MARG = 0.4f;
constexpr int WPAD   = 100352;              // 392*256
constexpr int NT2    = 392;                 // class tiles (BN=256)
constexpr int NT_FB  = 782;                 // fallback class tiles (BN=128)
constexpr int TSLOT  = 256 * 32;            // shorts per A-or-B ring slot (16 KB)

typedef __attribute__((ext_vector_type(8))) short bf16x8;   // 8 bf16 (4 VGPRs)
typedef __attribute__((ext_vector_type(4))) float f32x4;
typedef __attribute__((address_space(1))) const void gvoid_t;
typedef __attribute__((address_space(3))) void lvoid_t;

__device__ __forceinline__ unsigned int f2bf(float x) {
    union { float f; unsigned int u; } v; v.f = x;
    return (v.u + 0x7FFFu + ((v.u >> 16) & 1u)) >> 16;   // RNE to bf16 bits
}

__device__ __forceinline__ float wave_sum(float s) {
    #pragma unroll
    for (int m = 1; m < 64; m <<= 1) s += __shfl_xor(s, m, 64);
    return s;
}

// ---- per-row norm of embs -> g[i], normalized bf16 ehat ----
__global__ __launch_bounds__(256) void prep_embs(const float* __restrict__ embs,
                                                 float* __restrict__ g,
                                                 unsigned short* __restrict__ ehat) {
    const int row  = blockIdx.x * 4 + (threadIdx.x >> 6);
    const int lane = threadIdx.x & 63;
    const float4* src = (const float4*)(embs + (size_t)row * DDIM + lane * 8);
    const float4 a = src[0], b = src[1];
    float ss = a.x*a.x + a.y*a.y + a.z*a.z + a.w*a.w
             + b.x*b.x + b.y*b.y + b.z*b.z + b.w*b.w;
    ss = wave_sum(ss);
    const float norm = sqrtf(ss);
    const float rn = 1.f / norm;
    if (lane == 0) {
        float gg = (norm - 20.f) / sqrtf(10000.f + 1e-3f) * 0.333f;
        gg = fminf(fmaxf(gg, -1.f), 1.f);
        g[row] = gg;
    }
    uint4 pk;
    pk.x = f2bf(a.x*rn) | (f2bf(a.y*rn) << 16);
    pk.y = f2bf(a.z*rn) | (f2bf(a.w*rn) << 16);
    pk.z = f2bf(b.x*rn) | (f2bf(b.y*rn) << 16);
    pk.w = f2bf(b.z*rn) | (f2bf(b.w*rn) << 16);
    *(uint4*)(ehat + (size_t)row * DDIM + lane * 8) = pk;
}

// ---- normalized bf16 weight ----
__global__ __launch_bounds__(256) void prep_what(const float* __restrict__ w,
                                                 unsigned short* __restrict__ what) {
    const int row  = blockIdx.x * 4 + (threadIdx.x >> 6);
    const int lane = threadIdx.x & 63;
    const float4* src = (const float4*)(w + (size_t)row * DDIM + lane * 8);
    const float4 a = src[0], b = src[1];
    float ss = a.x*a.x + a.y*a.y + a.z*a.z + a.w*a.w
             + b.x*b.x + b.y*b.y + b.z*b.z + b.w*b.w;
    ss = wave_sum(ss);
    const float rn = rsqrtf(ss);
    uint4 pk;
    pk.x = f2bf(a.x*rn) | (f2bf(a.y*rn) << 16);
    pk.y = f2bf(a.z*rn) | (f2bf(a.w*rn) << 16);
    pk.z = f2bf(b.x*rn) | (f2bf(b.y*rn) << 16);
    pk.w = f2bf(b.z*rn) | (f2bf(b.w*rn) << 16);
    *(uint4*)(what + (size_t)row * DDIM + lane * 8) = pk;
}

// ---- fallback helper: 1/||weight[c]|| ----
__global__ __launch_bounds__(256) void prep_wnorm(const float* __restrict__ w,
                                                  float* __restrict__ rnormw) {
    const int row  = blockIdx.x * 4 + (threadIdx.x >> 6);
    const int lane = threadIdx.x & 63;
    const float4* src = (const float4*)(w + (size_t)row * DDIM + lane * 8);
    const float4 a = src[0], b = src[1];
    float ss = a.x*a.x + a.y*a.y + a.z*a.z + a.w*a.w
             + b.x*b.x + b.y*b.y + b.z*b.z + b.w*b.w;
    ss = wave_sum(ss);
    if (lane == 0) rnormw[row] = 1.f / sqrtf(ss);
}

// ==== BK=32 swizzle: physical chunk pc = logical chunk ^ ((row>>1)&3) ====
// stage: linear LDS dest (gload_lds writes base+lane*16B), inverse-swizzled global source.
__device__ __forceinline__ void stage_tile(const unsigned short* __restrict__ src,
                                           int grow0, unsigned short* tile,
                                           int kbase, int tid, int wv) {
    #pragma unroll
    for (int i = 0; i < 2; ++i) {
        const int r  = i * 128 + (tid >> 2);            // row 0..255
        const int lc = (tid & 3) ^ ((r >> 1) & 3);      // logical 16B chunk at physical tid&3
        const unsigned short* g = src + (size_t)(grow0 + r) * DDIM + kbase + lc * 8;
        __builtin_amdgcn_global_load_lds((gvoid_t*)g,
            (lvoid_t*)(tile + i * 4096 + wv * 512), 16, 0, 0);  // wave-uniform base
    }
}
// fragment read: logical chunk = lane>>4, swizzled to physical
__device__ __forceinline__ bf16x8 frag32(const unsigned short* tile, int row, int lane) {
    const int pc = (lane >> 4) ^ ((row >> 1) & 3);
    return *(const bf16x8*)(tile + row * 32 + pc * 8);
}

// ==== 256x256 / BK=32, 4-slot ring, counted-vmcnt deep pipeline ====
__global__ __launch_bounds__(512, 2) void gemm256p(
        const unsigned short* __restrict__ ehat,   // [1024][512] bf16
        const unsigned short* __restrict__ what,   // [WPAD][512] bf16
        const int* __restrict__ labels,
        float* __restrict__ psum,                  // [1024][NT2]
        float* __restrict__ dlab)
{
    __shared__ __align__(16) unsigned short Abuf[4 * TSLOT];  // 64 KB
    __shared__ __align__(16) unsigned short Bbuf[4 * TSLOT];  // 64 KB

    const int tid  = threadIdx.x;
    const int lane = tid & 63;
    const int wv   = tid >> 6;
    const int wr   = wv >> 2;     // 0..1  (128 rows each)
    const int wc   = wv & 3;      // 0..3  (64 cols each)

    // T1: bijective XCD swizzle; grid = 1568 = 8*196. Consecutive wgid share tile_c.
    const int nchunk = (int)gridDim.x >> 3;
    const int wgid   = ((int)blockIdx.x & 7) * nchunk + ((int)blockIdx.x >> 3);
    const int tile_c = wgid >> 2;
    const int tile_r = wgid & 3;
    const int row0   = tile_r * 256;
    const int col0   = tile_c * 256;

    f32x4 acc[8][4];
    #pragma unroll
    for (int m = 0; m < 8; ++m)
        #pragma unroll
        for (int n = 0; n < 4; ++n) acc[m][n] = f32x4{0.f, 0.f, 0.f, 0.f};

    // prologue: stage K-tiles 0,1,2 into ring slots 0,1,2 (12 loads/thread)
    #pragma unroll
    for (int t = 0; t < 3; ++t) {
        stage_tile(ehat, row0, Abuf + t * TSLOT, t * 32, tid, wv);
        stage_tile(what, col0, Bbuf + t * TSLOT, t * 32, tid, wv);
    }
    asm volatile("s_waitcnt vmcnt(8)" ::: "memory");   // tile 0 landed
    __builtin_amdgcn_s_barrier();

    auto body = [&](int h, bool do_stage) {
        if (do_stage) {                                // stage tile h+3 (3-tile lead)
            const int hn = h + 3;
            stage_tile(ehat, row0, Abuf + (hn & 3) * TSLOT, hn * 32, tid, wv);
            stage_tile(what, col0, Bbuf + (hn & 3) * TSLOT, hn * 32, tid, wv);
        }
        const unsigned short* At = Abuf + (h & 3) * TSLOT;
        const unsigned short* Bt = Bbuf + (h & 3) * TSLOT;
        bf16x8 af[8], bf[4];
        #pragma unroll
        for (int m = 0; m < 8; ++m)
            af[m] = frag32(At, wr * 128 + m * 16 + (lane & 15), lane);
        #pragma unroll
        for (int n = 0; n < 4; ++n)
            bf[n] = frag32(Bt, wc * 64 + n * 16 + (lane & 15), lane);
        __builtin_amdgcn_s_setprio(1);
        #pragma unroll
        for (int m = 0; m < 8; ++m)
            #pragma unroll
            for (int n = 0; n < 4; ++n)
                acc[m][n] = __builtin_amdgcn_mfma_f32_16x16x32_bf16(af[m], bf[n], acc[m][n], 0, 0, 0);
        __builtin_amdgcn_s_setprio(0);
    };

    for (int h = 0; h < 13; ++h) {
        body(h, true);
        // counted wait: leaves t_{h+2},t_{h+3} (8 loads) in flight; t_{h+1} complete
        asm volatile("s_waitcnt vmcnt(8)" ::: "memory");
        __builtin_amdgcn_s_barrier();
    }
    body(13, false);
    asm volatile("s_waitcnt vmcnt(4)" ::: "memory");   // t14 complete
    __builtin_amdgcn_s_barrier();
    body(14, false);
    asm volatile("s_waitcnt vmcnt(0)" ::: "memory");   // t15 complete
    __builtin_amdgcn_s_barrier();
    body(15, false);

    // ---- epilogue: clip, label capture, exp-sum; red buffer in slot 0 (last read h=12) ----
    float* red = (float*)&Abuf[0];                     // 4*256 floats
    #pragma unroll
    for (int m = 0; m < 8; ++m) {
        #pragma unroll
        for (int j = 0; j < 4; ++j) {
            const int lrow  = wr * 128 + m * 16 + ((lane >> 4) << 2) + j;
            const int r_abs = row0 + lrow;
            const int lab   = labels[r_abs];
            float s = 0.f;
            #pragma unroll
            for (int n = 0; n < 4; ++n) {
                const int c_abs = col0 + wc * 64 + n * 16 + (lane & 15);
                float v = acc[m][n][j];
                v = fminf(fmaxf(v, -0.999f), 0.999f);
                if (c_abs == lab) dlab[r_abs] = v;
                if (c_abs < C_CLS) s += __expf(64.f * v - 64.f);
            }
            #pragma unroll
            for (int msk = 1; msk < 16; msk <<= 1) s += __shfl_xor(s, msk, 64);
            if ((lane & 15) == 0) red[wc * 256 + lrow] = s;
        }
    }
    __syncthreads();
    for (int t = tid; t < 256; t += 512)
        psum[(size_t)(row0 + t) * NT2 + tile_c] = red[t] + red[256 + t] + red[512 + t] + red[768 + t];
}

// ==== fallback 128^2 GEMM (round-1 verified path, fp32 weight) ====
__global__ __launch_bounds__(256, 2) void gemm_fused_fb(
        const unsigned short* __restrict__ ehat,
        const float* __restrict__ weight,
        const float* __restrict__ rnormw,
        const int* __restrict__ labels,
        float* __restrict__ psum,
        float* __restrict__ dlab)
{
    constexpr int BM = 128, BN = 128, BK = 32;
    __shared__ __align__(16) unsigned short Asf[BM * BK];
    __shared__ __align__(16) unsigned short Bsf[BN * BK];
    __shared__ float redbuf[2][BM];

    const int bid    = blockIdx.x;
    const int tile_c = bid >> 3;
    const int tile_r = bid & 7;
    const int row0   = tile_r * BM;
    const int col0   = tile_c * BN;

    const int tid  = threadIdx.x;
    const int lane = tid & 63;
    const int wv   = tid >> 6;
    const int wr   = wv >> 1;
    const int wc   = wv & 1;

    f32x4 acc[4][4];
    #pragma unroll
    for (int m = 0; m < 4; ++m)
        #pragma unroll
        for (int n = 0; n < 4; ++n) acc[m][n] = f32x4{0.f, 0.f, 0.f, 0.f};

    const int kq    = tid & 7;
    const int brow0 = tid >> 3;
    int   cidx[4];
    float rnv[4];
    #pragma unroll
    for (int p = 0; p < 4; ++p) {
        int c = col0 + p * 32 + brow0;
        c = c < C_CLS ? c : C_CLS - 1;
        cidx[p] = c;
        rnv[p]  = rnormw[c];
    }

    for (int kt = 0; kt < DDIM / BK; ++kt) {
        const int kbase = kt * BK;
        #pragma unroll
        for (int call = 0; call < 2; ++call) {
            const int chunk = call * 256 + tid;
            const uint4 d = *(const uint4*)(ehat + (size_t)(row0 + (chunk >> 2)) * DDIM
                                            + kbase + (chunk & 3) * 8);
            *(uint4*)(Asf + chunk * 8) = d;
        }
        #pragma unroll
        for (int p = 0; p < 4; ++p) {
            const float4 wd = *(const float4*)(weight + (size_t)cidx[p] * DDIM + kbase + kq * 4);
            const float r = rnv[p];
            const unsigned int lo = f2bf(wd.x * r) | (f2bf(wd.y * r) << 16);
            const unsigned int hi = f2bf(wd.z * r) | (f2bf(wd.w * r) << 16);
            *(uint2*)(Bsf + (p * 32 + brow0) * BK + kq * 4) = make_uint2(lo, hi);
        }
        __syncthreads();
        bf16x8 af[4], bfr[4];
        const int lr  = lane & 15;
        const int lko = (lane >> 4) * 8;
        #pragma unroll
        for (int m = 0; m < 4; ++m)
            af[m] = *(const bf16x8*)(Asf + (wr * 64 + m * 16 + lr) * BK + lko);
        #pragma unroll
        for (int n = 0; n < 4; ++n)
            bfr[n] = *(const bf16x8*)(Bsf + (wc * 64 + n * 16 + lr) * BK + lko);
        #pragma unroll
        for (int m = 0; m < 4; ++m)
            #pragma unroll
            for (int n = 0; n < 4; ++n)
                acc[m][n] = __builtin_amdgcn_mfma_f32_16x16x32_bf16(af[m], bfr[n], acc[m][n], 0, 0, 0);
        __syncthreads();
    }

    #pragma unroll
    for (int m = 0; m < 4; ++m) {
        #pragma unroll
        for (int j = 0; j < 4; ++j) {
            const int lrow  = wr * 64 + m * 16 + ((lane >> 4) << 2) + j;
            const int r_abs = row0 + lrow;
            const int lab   = labels[r_abs];
            float s = 0.f;
            #pragma unroll
            for (int n = 0; n < 4; ++n) {
                const int c_abs = col0 + wc * 64 + n * 16 + (lane & 15);
                float v = acc[m][n][j];
                v = fminf(fmaxf(v, -0.999f), 0.999f);
                if (c_abs == lab) dlab[r_abs] = v;
                if (c_abs < C_CLS) s += __expf(64.f * v - 64.f);
            }
            #pragma unroll
            for (int msk = 1; msk < 16; msk <<= 1) s += __shfl_xor(s, msk, 64);
            if ((lane & 15) == 0) redbuf[wc][lrow] = s;
        }
    }
    __syncthreads();
    for (int t = tid; t < BM; t += 256)
        psum[(size_t)(row0 + t) * NT_FB + tile_c] = redbuf[0][t] + redbuf[1][t];
}

// ---- per-row combine + margin correction at label ----
__global__ __launch_bounds__(256) void reduce_rows(const float* __restrict__ psum,
                                                   const float* __restrict__ dlab,
                                                   const float* __restrict__ g,
                                                   float* __restrict__ losses, int nt) {
    const int row  = blockIdx.x * 4 + (threadIdx.x >> 6);
    const int lane = threadIdx.x & 63;
    const float* p = psum + (size_t)row * nt;
    float s = 0.f;
    for (int t = lane; t < nt; t += 64) s += p[t];
    s = wave_sum(s);
    if (lane == 0) {
        const float v  = dlab[row];
        const float gg = g[row];
        float th = acosf(v) - MARG * gg;
        th = fminf(fmaxf(th, 0.f), 3.14159265358979323846f);
        const float vm = cosf(th) - (1.f + MARG) * gg;
        s = s - __expf(64.f * v - 64.f) + __expf(64.f * vm - 64.f);
        losses[row] = 64.f + logf(s) - 64.f * vm;
    }
}

__global__ __launch_bounds__(256) void final_mean(const float* __restrict__ losses,
                                                  float* __restrict__ out) {
    const int tid = threadIdx.x;
    float s = 0.f;
    #pragma unroll
    for (int i = 0; i < 4; ++i) s += losses[tid + i * 256];
    s = wave_sum(s);
    __shared__ float red[4];
    if ((tid & 63) == 0) red[tid >> 6] = s;
    __syncthreads();
    if (tid == 0) out[0] = (red[0] + red[1] + red[2] + red[3]) * (1.f / 1024.f);
}

extern "C" void kernel_launch(void* const* d_in, const int* in_sizes, int n_in,
                              void* d_out, int out_size, void* d_ws, size_t ws_size,
                              hipStream_t stream) {
    const float* embs   = (const float*)d_in[0];
    const float* weight = (const float*)d_in[1];
    const int*   labels = (const int*)d_in[2];
    float* out = (float*)d_out;
    float* ws  = (float*)d_ws;

    const size_t WHAT_F = (size_t)WPAD * DDIM / 2;
    const size_t EHAT_F = (size_t)N_ROWS * DDIM / 2;
    const size_t PSUM_F = (size_t)N_ROWS * NT2;
    const size_t NEED_F = WHAT_F + EHAT_F + PSUM_F + 3 * 1024;

    if (ws_size >= NEED_F * sizeof(float)) {
        unsigned short* what = (unsigned short*)ws;
        unsigned short* ehat = (unsigned short*)(ws + WHAT_F);
        float* psum   = ws + WHAT_F + EHAT_F;
        float* gbuf   = psum + PSUM_F;
        float* dlab   = gbuf + 1024;
        float* losses = dlab + 1024;

        prep_embs<<<N_ROWS / 4, 256, 0, stream>>>(embs, gbuf, ehat);
        prep_what<<<C_CLS / 4, 256, 0, stream>>>(weight, what);
        gemm256p<<<NT2 * 4, 512, 0, stream>>>(ehat, what, labels, psum, dlab);
        reduce_rows<<<N_ROWS / 4, 256, 0, stream>>>(psum, dlab, gbuf, losses, NT2);
        final_mean<<<1, 256, 0, stream>>>(losses, out);
    } else {
        float* rnormw = ws + 0;
        float* gbuf   = ws + 100352;
        float* dlab   = ws + 101376;
        float* losses = ws + 102400;
        unsigned short* ehat = (unsigned short*)(ws + 103424);
        float* psum   = ws + 103424 + 262144;

        prep_embs <<<N_ROWS / 4, 256, 0, stream>>>(embs, gbuf, ehat);
        prep_wnorm<<<C_CLS / 4, 256, 0, stream>>>(weight, rnormw);
        gemm_fused_fb<<<NT_FB * 8, 256, 0, stream>>>(ehat, weight, rnormw, labels, psum, dlab);
        reduce_rows<<<N_ROWS / 4, 256, 0, stream>>>(psum, dlab, gbuf, losses, NT_FB);
        final_mean<<<1, 256, 0, stream>>>(losses, out);
    }
}

// Round 5
// 221.696 us; speedup vs baseline: 1.0043x; 1.0043x over previous
//
#include <hip/hip_runtime.h>
#include <math.h>

constexpr int N_ROWS = 1024;
constexpr int DDIM   = 512;
constexpr int C_CLS  = 100000;
constexpr float MARG = 0.4f;
constexpr int WPAD   = 100352;              // 392*256
constexpr int NT2    = 392;                 // class tiles (BN=256)
constexpr int NT_FB  = 782;                 // fallback class tiles (BN=128)
constexpr int TILE   = 256 * 64;            // shorts per operand per buffer (32 KB)

typedef __attribute__((ext_vector_type(8))) short bf16x8;   // 8 bf16 (4 VGPRs)
typedef __attribute__((ext_vector_type(4))) float f32x4;
typedef __attribute__((address_space(1))) const void gvoid_t;
typedef __attribute__((address_space(3))) void lvoid_t;

#define WAITV(N) asm volatile("s_waitcnt vmcnt(" #N ")" ::: "memory")

__device__ __forceinline__ unsigned int f2bf(float x) {
    union { float f; unsigned int u; } v; v.f = x;
    return (v.u + 0x7FFFu + ((v.u >> 16) & 1u)) >> 16;   // RNE to bf16 bits
}

__device__ __forceinline__ float wave_sum(float s) {
    #pragma unroll
    for (int m = 1; m < 64; m <<= 1) s += __shfl_xor(s, m, 64);
    return s;
}

// ---- per-row norm of embs -> g[i], normalized bf16 ehat ----
__global__ __launch_bounds__(256) void prep_embs(const float* __restrict__ embs,
                                                 float* __restrict__ g,
                                                 unsigned short* __restrict__ ehat) {
    const int row  = blockIdx.x * 4 + (threadIdx.x >> 6);
    const int lane = threadIdx.x & 63;
    const float4* src = (const float4*)(embs + (size_t)row * DDIM + lane * 8);
    const float4 a = src[0], b = src[1];
    float ss = a.x*a.x + a.y*a.y + a.z*a.z + a.w*a.w
             + b.x*b.x + b.y*b.y + b.z*b.z + b.w*b.w;
    ss = wave_sum(ss);
    const float norm = sqrtf(ss);
    const float rn = 1.f / norm;
    if (lane == 0) {
        float gg = (norm - 20.f) / sqrtf(10000.f + 1e-3f) * 0.333f;
        gg = fminf(fmaxf(gg, -1.f), 1.f);
        g[row] = gg;
    }
    uint4 pk;
    pk.x = f2bf(a.x*rn) | (f2bf(a.y*rn) << 16);
    pk.y = f2bf(a.z*rn) | (f2bf(a.w*rn) << 16);
    pk.z = f2bf(b.x*rn) | (f2bf(b.y*rn) << 16);
    pk.w = f2bf(b.z*rn) | (f2bf(b.w*rn) << 16);
    *(uint4*)(ehat + (size_t)row * DDIM + lane * 8) = pk;
}

// ---- normalized bf16 weight ----
__global__ __launch_bounds__(256) void prep_what(const float* __restrict__ w,
                                                 unsigned short* __restrict__ what) {
    const int row  = blockIdx.x * 4 + (threadIdx.x >> 6);
    const int lane = threadIdx.x & 63;
    const float4* src = (const float4*)(w + (size_t)row * DDIM + lane * 8);
    const float4 a = src[0], b = src[1];
    float ss = a.x*a.x + a.y*a.y + a.z*a.z + a.w*a.w
             + b.x*b.x + b.y*b.y + b.z*b.z + b.w*b.w;
    ss = wave_sum(ss);
    const float rn = rsqrtf(ss);
    uint4 pk;
    pk.x = f2bf(a.x*rn) | (f2bf(a.y*rn) << 16);
    pk.y = f2bf(a.z*rn) | (f2bf(a.w*rn) << 16);
    pk.z = f2bf(b.x*rn) | (f2bf(b.y*rn) << 16);
    pk.w = f2bf(b.z*rn) | (f2bf(b.w*rn) << 16);
    *(uint4*)(what + (size_t)row * DDIM + lane * 8) = pk;
}

// ---- fallback helper: 1/||weight[c]|| ----
__global__ __launch_bounds__(256) void prep_wnorm(const float* __restrict__ w,
                                                  float* __restrict__ rnormw) {
    const int row  = blockIdx.x * 4 + (threadIdx.x >> 6);
    const int lane = threadIdx.x & 63;
    const float4* src = (const float4*)(w + (size_t)row * DDIM + lane * 8);
    const float4 a = src[0], b = src[1];
    float ss = a.x*a.x + a.y*a.y + a.z*a.z + a.w*a.w
             + b.x*b.x + b.y*b.y + b.z*b.z + b.w*b.w;
    ss = wave_sum(ss);
    if (lane == 0) rnormw[row] = 1.f / sqrtf(ss);
}

// ==== BK=64 tile: [256 rows][8 chunks of 16B]; phys chunk = logical ^ (row&7) ====
// A half g = rows with bit6==g; B half g = rows with bit5==g (each 128 rows = 16 KB).
// stage: linear LDS dest per 8-row slab (gload_lds writes base+lane*16B),
// inverse-swizzled global source. 2 loads/thread per half.
__device__ __forceinline__ void stageA(const unsigned short* __restrict__ src, int grow0,
                                       unsigned short* tile, int g, int kbase,
                                       int wv, int lane) {
    const int lr = lane >> 3;                 // row in slab
    const int lc = (lane & 7) ^ lr;           // logical chunk for physical slot lane&7
    #pragma unroll
    for (int i = 0; i < 2; ++i) {
        const int s  = i * 8 + wv;            // slab 0..15
        const int rb = ((s >> 3) << 7) | (g << 6) | ((s & 7) << 3);
        const unsigned short* gp = src + (size_t)(grow0 + rb + lr) * DDIM + kbase + lc * 8;
        __builtin_amdgcn_global_load_lds((gvoid_t*)gp, (lvoid_t*)(tile + rb * 64), 16, 0, 0);
    }
}
__device__ __forceinline__ void stageB(const unsigned short* __restrict__ src, int grow0,
                                       unsigned short* tile, int g, int kbase,
                                       int wv, int lane) {
    const int lr = lane >> 3;
    const int lc = (lane & 7) ^ lr;
    #pragma unroll
    for (int i = 0; i < 2; ++i) {
        const int s  = i * 8 + wv;
        const int rb = ((s >> 2) << 6) | (g << 5) | ((s & 3) << 3);
        const unsigned short* gp = src + (size_t)(grow0 + rb + lr) * DDIM + kbase + lc * 8;
        __builtin_amdgcn_global_load_lds((gvoid_t*)gp, (lvoid_t*)(tile + rb * 64), 16, 0, 0);
    }
}
// fragment read: row includes lane&15 (16-aligned base) so row&7 == lane&7
__device__ __forceinline__ bf16x8 frag64(const unsigned short* tile, int row, int ks, int lane) {
    const int pc = ((ks << 2) + (lane >> 4)) ^ (lane & 7);
    return *(const bf16x8*)(tile + row * 64 + pc * 8);
}

// ==== 256x256 / BK=64 / 2 dbuf / 4 interleaved phases per K-tile ====
__global__ __launch_bounds__(512, 2) void gemm256q(
        const unsigned short* __restrict__ ehat,   // [1024][512] bf16
        const unsigned short* __restrict__ what,   // [WPAD][512] bf16
        const int* __restrict__ labels,
        float* __restrict__ psum,                  // [1024][NT2]
        float* __restrict__ dlab)
{
    __shared__ __align__(16) unsigned short Abuf[2 * TILE];  // 64 KB
    __shared__ __align__(16) unsigned short Bbuf[2 * TILE];  // 64 KB

    const int tid  = threadIdx.x;
    const int lane = tid & 63;
    const int wv   = tid >> 6;
    const int wr   = wv >> 2;     // 0..1 : 128-row half
    const int wc   = wv & 3;      // 0..3 : 64-col quarter
    const int lr15 = lane & 15;

    // T1: bijective XCD swizzle; grid = 1568 = 8*196; consecutive wgid share tile_c.
    const int nchunk = (int)gridDim.x >> 3;
    const int wgid   = ((int)blockIdx.x & 7) * nchunk + ((int)blockIdx.x >> 3);
    const int tile_c = wgid >> 2;
    const int tile_r = wgid & 3;
    const int row0   = tile_r * 256;
    const int col0   = tile_c * 256;

    f32x4 acc[8][4];
    #pragma unroll
    for (int m = 0; m < 8; ++m)
        #pragma unroll
        for (int n = 0; n < 4; ++n) acc[m][n] = f32x4{0.f, 0.f, 0.f, 0.f};

    // prologue: Ag0(0),Bg0(0),Ag1(0),Bg1(0),Ag0(1),Bg0(1)  (12 loads/thread)
    stageA(ehat, row0, Abuf, 0, 0, wv, lane);
    stageB(what, col0, Bbuf, 0, 0, wv, lane);
    stageA(ehat, row0, Abuf, 1, 0, wv, lane);
    stageB(what, col0, Bbuf, 1, 0, wv, lane);
    stageA(ehat, row0, Abuf + TILE, 0, 64, wv, lane);
    stageB(what, col0, Bbuf + TILE, 0, 64, wv, lane);
    WAITV(8);                                  // Ag0(0),Bg0(0) landed
    __builtin_amdgcn_s_barrier();

    for (int t = 0; t < 8; ++t) {
        unsigned short* curA = Abuf + (t & 1) * TILE;
        unsigned short* curB = Bbuf + (t & 1) * TILE;
        unsigned short* nxtA = Abuf + ((t & 1) ^ 1) * TILE;
        unsigned short* nxtB = Bbuf + ((t & 1) ^ 1) * TILE;
        bf16x8 af[4][2], bfv[2][2][2];

        // -------- phase 1: quadrant (mh=0, nh=0); stage Ag1(t+1) --------
        #pragma unroll
        for (int m = 0; m < 4; ++m)
            #pragma unroll
            for (int ks = 0; ks < 2; ++ks)
                af[m][ks] = frag64(curA, wr * 128 + m * 16 + lr15, ks, lane);
        #pragma unroll
        for (int n = 0; n < 2; ++n)
            #pragma unroll
            for (int ks = 0; ks < 2; ++ks)
                bfv[0][n][ks] = frag64(curB, wc * 64 + n * 16 + lr15, ks, lane);
        if (t < 7) stageA(ehat, row0, nxtA, 1, (t + 1) * 64, wv, lane);
        __builtin_amdgcn_sched_barrier(0);
        __builtin_amdgcn_s_barrier();
        asm volatile("s_waitcnt lgkmcnt(0)" ::: "memory");
        __builtin_amdgcn_sched_barrier(0);
        __builtin_amdgcn_s_setprio(1);
        #pragma unroll
        for (int m = 0; m < 4; ++m)
            #pragma unroll
            for (int n = 0; n < 2; ++n)
                #pragma unroll
                for (int ks = 0; ks < 2; ++ks)
                    acc[m][n] = __builtin_amdgcn_mfma_f32_16x16x32_bf16(af[m][ks], bfv[0][n][ks], acc[m][n], 0, 0, 0);
        __builtin_amdgcn_s_setprio(0);
        if (t < 7) { WAITV(6); } else { WAITV(0); }   // Bg1(t),Ag1(t) guaranteed
        __builtin_amdgcn_s_barrier();

        // -------- phase 2: quadrant (mh=0, nh=1); stage Bg1(t+1) --------
        #pragma unroll
        for (int n = 0; n < 2; ++n)
            #pragma unroll
            for (int ks = 0; ks < 2; ++ks)
                bfv[1][n][ks] = frag64(curB, wc * 64 + 32 + n * 16 + lr15, ks, lane);
        if (t < 7) stageB(what, col0, nxtB, 1, (t + 1) * 64, wv, lane);
        __builtin_amdgcn_sched_barrier(0);
        __builtin_amdgcn_s_barrier();
        asm volatile("s_waitcnt lgkmcnt(0)" ::: "memory");
        __builtin_amdgcn_sched_barrier(0);
        __builtin_amdgcn_s_setprio(1);
        #pragma unroll
        for (int m = 0; m < 4; ++m)
            #pragma unroll
            for (int n = 0; n < 2; ++n)
                #pragma unroll
                for (int ks = 0; ks < 2; ++ks)
                    acc[m][2 + n] = __builtin_amdgcn_mfma_f32_16x16x32_bf16(af[m][ks], bfv[1][n][ks], acc[m][2 + n], 0, 0, 0);
        __builtin_amdgcn_s_setprio(0);
        __builtin_amdgcn_s_barrier();

        // -------- phase 3: quadrant (mh=1, nh=0); stage Ag0(t+2) into cur --------
        #pragma unroll
        for (int m = 0; m < 4; ++m)
            #pragma unroll
            for (int ks = 0; ks < 2; ++ks)
                af[m][ks] = frag64(curA, wr * 128 + 64 + m * 16 + lr15, ks, lane);
        if (t < 6) stageA(ehat, row0, curA, 0, (t + 2) * 64, wv, lane);
        __builtin_amdgcn_sched_barrier(0);
        __builtin_amdgcn_s_barrier();
        asm volatile("s_waitcnt lgkmcnt(0)" ::: "memory");
        __builtin_amdgcn_sched_barrier(0);
        __builtin_amdgcn_s_setprio(1);
        #pragma unroll
        for (int m = 0; m < 4; ++m)
            #pragma unroll
            for (int n = 0; n < 2; ++n)
                #pragma unroll
                for (int ks = 0; ks < 2; ++ks)
                    acc[4 + m][n] = __builtin_amdgcn_mfma_f32_16x16x32_bf16(af[m][ks], bfv[0][n][ks], acc[4 + m][n], 0, 0, 0);
        __builtin_amdgcn_s_setprio(0);
        __builtin_amdgcn_s_barrier();

        // -------- phase 4: quadrant (mh=1, nh=1); stage Bg0(t+2) into cur --------
        if (t < 6) stageB(what, col0, curB, 0, (t + 2) * 64, wv, lane);
        __builtin_amdgcn_sched_barrier(0);
        __builtin_amdgcn_s_barrier();
        __builtin_amdgcn_s_setprio(1);
        #pragma unroll
        for (int m = 0; m < 4; ++m)
            #pragma unroll
            for (int n = 0; n < 2; ++n)
                #pragma unroll
                for (int ks = 0; ks < 2; ++ks)
                    acc[4 + m][2 + n] = __builtin_amdgcn_mfma_f32_16x16x32_bf16(af[m][ks], bfv[1][n][ks], acc[4 + m][2 + n], 0, 0, 0);
        __builtin_amdgcn_s_setprio(0);
        if (t < 6) { WAITV(8); } else if (t == 6) { WAITV(4); } else { WAITV(0); }
        __builtin_amdgcn_s_barrier();
    }

    // ---- epilogue: clip, label capture, exp-sum; LDS reused as reduction buffer ----
    float* red = (float*)&Abuf[0];                     // 4*256 floats
    #pragma unroll
    for (int m = 0; m < 8; ++m) {
        #pragma unroll
        for (int j = 0; j < 4; ++j) {
            const int lrow  = wr * 128 + m * 16 + ((lane >> 4) << 2) + j;
            const int r_abs = row0 + lrow;
            const int lab   = labels[r_abs];
            float s = 0.f;
            #pragma unroll
            for (int n = 0; n < 4; ++n) {
                const int c_abs = col0 + wc * 64 + n * 16 + (lane & 15);
                float v = acc[m][n][j];
                v = fminf(fmaxf(v, -0.999f), 0.999f);
                if (c_abs == lab) dlab[r_abs] = v;
                if (c_abs < C_CLS) s += __expf(64.f * v - 64.f);
            }
            #pragma unroll
            for (int msk = 1; msk < 16; msk <<= 1) s += __shfl_xor(s, msk, 64);
            if ((lane & 15) == 0) red[wc * 256 + lrow] = s;
        }
    }
    __syncthreads();
    for (int t = tid; t < 256; t += 512)
        psum[(size_t)(row0 + t) * NT2 + tile_c] = red[t] + red[256 + t] + red[512 + t] + red[768 + t];
}

// ==== fallback 128^2 GEMM (round-1 verified path, fp32 weight) ====
__global__ __launch_bounds__(256, 2) void gemm_fused_fb(
        const unsigned short* __restrict__ ehat,
        const float* __restrict__ weight,
        const float* __restrict__ rnormw,
        const int* __restrict__ labels,
        float* __restrict__ psum,
        float* __restrict__ dlab)
{
    constexpr int BM = 128, BN = 128, BK = 32;
    __shared__ __align__(16) unsigned short Asf[BM * BK];
    __shared__ __align__(16) unsigned short Bsf[BN * BK];
    __shared__ float redbuf[2][BM];

    const int bid    = blockIdx.x;
    const int tile_c = bid >> 3;
    const int tile_r = bid & 7;
    const int row0   = tile_r * BM;
    const int col0   = tile_c * BN;

    const int tid  = threadIdx.x;
    const int lane = tid & 63;
    const int wv   = tid >> 6;
    const int wr   = wv >> 1;
    const int wc   = wv & 1;

    f32x4 acc[4][4];
    #pragma unroll
    for (int m = 0; m < 4; ++m)
        #pragma unroll
        for (int n = 0; n < 4; ++n) acc[m][n] = f32x4{0.f, 0.f, 0.f, 0.f};

    const int kq    = tid & 7;
    const int brow0 = tid >> 3;
    int   cidx[4];
    float rnv[4];
    #pragma unroll
    for (int p = 0; p < 4; ++p) {
        int c = col0 + p * 32 + brow0;
        c = c < C_CLS ? c : C_CLS - 1;
        cidx[p] = c;
        rnv[p]  = rnormw[c];
    }

    for (int kt = 0; kt < DDIM / BK; ++kt) {
        const int kbase = kt * BK;
        #pragma unroll
        for (int call = 0; call < 2; ++call) {
            const int chunk = call * 256 + tid;
            const uint4 d = *(const uint4*)(ehat + (size_t)(row0 + (chunk >> 2)) * DDIM
                                            + kbase + (chunk & 3) * 8);
            *(uint4*)(Asf + chunk * 8) = d;
        }
        #pragma unroll
        for (int p = 0; p < 4; ++p) {
            const float4 wd = *(const float4*)(weight + (size_t)cidx[p] * DDIM + kbase + kq * 4);
            const float r = rnv[p];
            const unsigned int lo = f2bf(wd.x * r) | (f2bf(wd.y * r) << 16);
            const unsigned int hi = f2bf(wd.z * r) | (f2bf(wd.w * r) << 16);
            *(uint2*)(Bsf + (p * 32 + brow0) * BK + kq * 4) = make_uint2(lo, hi);
        }
        __syncthreads();
        bf16x8 af[4], bfr[4];
        const int lr  = lane & 15;
        const int lko = (lane >> 4) * 8;
        #pragma unroll
        for (int m = 0; m < 4; ++m)
            af[m] = *(const bf16x8*)(Asf + (wr * 64 + m * 16 + lr) * BK + lko);
        #pragma unroll
        for (int n = 0; n < 4; ++n)
            bfr[n] = *(const bf16x8*)(Bsf + (wc * 64 + n * 16 + lr) * BK + lko);
        #pragma unroll
        for (int m = 0; m < 4; ++m)
            #pragma unroll
            for (int n = 0; n < 4; ++n)
                acc[m][n] = __builtin_amdgcn_mfma_f32_16x16x32_bf16(af[m], bfr[n], acc[m][n], 0, 0, 0);
        __syncthreads();
    }

    #pragma unroll
    for (int m = 0; m < 4; ++m) {
        #pragma unroll
        for (int j = 0; j < 4; ++j) {
            const int lrow  = wr * 64 + m * 16 + ((lane >> 4) << 2) + j;
            const int r_abs = row0 + lrow;
            const int lab   = labels[r_abs];
            float s = 0.f;
            #pragma unroll
            for (int n = 0; n < 4; ++n) {
                const int c_abs = col0 + wc * 64 + n * 16 + (lane & 15);
                float v = acc[m][n][j];
                v = fminf(fmaxf(v, -0.999f), 0.999f);
                if (c_abs == lab) dlab[r_abs] = v;
                if (c_abs < C_CLS) s += __expf(64.f * v - 64.f);
            }
            #pragma unroll
            for (int msk = 1; msk < 16; msk <<= 1) s += __shfl_xor(s, msk, 64);
            if ((lane & 15) == 0) redbuf[wc][lrow] = s;
        }
    }
    __syncthreads();
    for (int t = tid; t < BM; t += 256)
        psum[(size_t)(row0 + t) * NT_FB + tile_c] = redbuf[0][t] + redbuf[1][t];
}

// ---- per-row combine + margin correction at label ----
__global__ __launch_bounds__(256) void reduce_rows(const float* __restrict__ psum,
                                                   const float* __restrict__ dlab,
                                                   const float* __restrict__ g,
                                                   float* __restrict__ losses, int nt) {
    const int row  = blockIdx.x * 4 + (threadIdx.x >> 6);
    const int lane = threadIdx.x & 63;
    const float* p = psum + (size_t)row * nt;
    float s = 0.f;
    for (int t = lane; t < nt; t += 64) s += p[t];
    s = wave_sum(s);
    if (lane == 0) {
        const float v  = dlab[row];
        const float gg = g[row];
        float th = acosf(v) - MARG * gg;
        th = fminf(fmaxf(th, 0.f), 3.14159265358979323846f);
        const float vm = cosf(th) - (1.f + MARG) * gg;
        s = s - __expf(64.f * v - 64.f) + __expf(64.f * vm - 64.f);
        losses[row] = 64.f + logf(s) - 64.f * vm;
    }
}

__global__ __launch_bounds__(256) void final_mean(const float* __restrict__ losses,
                                                  float* __restrict__ out) {
    const int tid = threadIdx.x;
    float s = 0.f;
    #pragma unroll
    for (int i = 0; i < 4; ++i) s += losses[tid + i * 256];
    s = wave_sum(s);
    __shared__ float red[4];
    if ((tid & 63) == 0) red[tid >> 6] = s;
    __syncthreads();
    if (tid == 0) out[0] = (red[0] + red[1] + red[2] + red[3]) * (1.f / 1024.f);
}

extern "C" void kernel_launch(void* const* d_in, const int* in_sizes, int n_in,
                              void* d_out, int out_size, void* d_ws, size_t ws_size,
                              hipStream_t stream) {
    const float* embs   = (const float*)d_in[0];
    const float* weight = (const float*)d_in[1];
    const int*   labels = (const int*)d_in[2];
    float* out = (float*)d_out;
    float* ws  = (float*)d_ws;

    const size_t WHAT_F = (size_t)WPAD * DDIM / 2;
    const size_t EHAT_F = (size_t)N_ROWS * DDIM / 2;
    const size_t PSUM_F = (size_t)N_ROWS * NT2;
    const size_t NEED_F = WHAT_F + EHAT_F + PSUM_F + 3 * 1024;

    if (ws_size >= NEED_F * sizeof(float)) {
        unsigned short* what = (unsigned short*)ws;
        unsigned short* ehat = (unsigned short*)(ws + WHAT_F);
        float* psum   = ws + WHAT_F + EHAT_F;
        float* gbuf   = psum + PSUM_F;
        float* dlab   = gbuf + 1024;
        float* losses = dlab + 1024;

        prep_embs<<<N_ROWS / 4, 256, 0, stream>>>(embs, gbuf, ehat);
        prep_what<<<C_CLS / 4, 256, 0, stream>>>(weight, what);
        gemm256q<<<NT2 * 4, 512, 0, stream>>>(ehat, what, labels, psum, dlab);
        reduce_rows<<<N_ROWS / 4, 256, 0, stream>>>(psum, dlab, gbuf, losses, NT2);
        final_mean<<<1, 256, 0, stream>>>(losses, out);
    } else {
        float* rnormw = ws + 0;
        float* gbuf   = ws + 100352;
        float* dlab   = ws + 101376;
        float* losses = ws + 102400;
        unsigned short* ehat = (unsigned short*)(ws + 103424);
        float* psum   = ws + 103424 + 262144;

        prep_embs <<<N_ROWS / 4, 256, 0, stream>>>(embs, gbuf, ehat);
        prep_wnorm<<<C_CLS / 4, 256, 0, stream>>>(weight, rnormw);
        gemm_fused_fb<<<NT_FB * 8, 256, 0, stream>>>(ehat, weight, rnormw, labels, psum, dlab);
        reduce_rows<<<N_ROWS / 4, 256, 0, stream>>>(psum, dlab, gbuf, losses, NT_FB);
        final_mean<<<1, 256, 0, stream>>>(losses, out);
    }
}

// Round 6
// 178.743 us; speedup vs baseline: 1.2456x; 1.2403x over previous
//
#include <hip/hip_runtime.h>
#include <math.h>

constexpr int N_ROWS = 1024;
constexpr int DDIM   = 512;
constexpr int C_CLS  = 100000;
constexpr float MARG = 0.4f;
constexpr int NT8    = 784;                 // class tiles (BN=128) main path
constexpr int WPAD8  = 100352;              // 784*128
constexpr int NT_FB  = 782;                 // fallback class tiles (BN=128, bf16 path)

typedef __attribute__((ext_vector_type(8))) short bf16x8;
typedef __attribute__((ext_vector_type(4))) float f32x4;
typedef __attribute__((ext_vector_type(4))) int   i32x4;
typedef __attribute__((ext_vector_type(8))) int   i32x8;
typedef __attribute__((address_space(1))) const void gvoid_t;
typedef __attribute__((address_space(3))) void lvoid_t;

#define WAITV(N) asm volatile("s_waitcnt vmcnt(" #N ")" ::: "memory")

__device__ __forceinline__ unsigned int f2bf(float x) {
    union { float f; unsigned int u; } v; v.f = x;
    return (v.u + 0x7FFFu + ((v.u >> 16) & 1u)) >> 16;
}

__device__ __forceinline__ float wave_sum(float s) {
    #pragma unroll
    for (int m = 1; m < 64; m <<= 1) s += __shfl_xor(s, m, 64);
    return s;
}

// ---- f32 -> e4m3fn (RNE, saturating) ----
#if __has_builtin(__builtin_amdgcn_cvt_pk_fp8_f32)
__device__ __forceinline__ unsigned int pk4_e4m3(float a, float b, float c, float d) {
    unsigned int u = (unsigned int)__builtin_amdgcn_cvt_pk_fp8_f32(a, b, 0, false);
    u = (unsigned int)__builtin_amdgcn_cvt_pk_fp8_f32(c, d, (int)u, true);
    return u;
}
#else
__device__ __forceinline__ unsigned int sw_e4m3(float x) {
    x = fminf(fmaxf(x, -448.f), 448.f);
    unsigned int s = (x < 0.f) ? 0x80u : 0u;
    float ax = fabsf(x);
    if (ax < 7.8125e-3f) {               // below min-normal 2^-6: denormal, quantum 2^-9
        int q = (int)rintf(ax * 512.f);
        if (q >= 8) return s | 0x08;
        return s | (unsigned int)q;
    }
    int e; float m = frexpf(ax, &e);     // ax = m*2^e, m in [0.5,1)
    int q = (int)rintf(m * 16.f);        // [8..16]
    if (q == 16) { q = 8; e += 1; }
    int E = e - 1 + 7;
    if (E > 15) { E = 15; q = 14; }
    return s | ((unsigned int)E << 3) | (unsigned int)(q - 8);
}
__device__ __forceinline__ unsigned int pk4_e4m3(float a, float b, float c, float d) {
    return sw_e4m3(a) | (sw_e4m3(b) << 8) | (sw_e4m3(c) << 16) | (sw_e4m3(d) << 24);
}
#endif

// ---- per-row norm of embs -> g[i], normalized fp8 ehat8 ----
__global__ __launch_bounds__(256) void prep_embs8(const float* __restrict__ embs,
                                                  float* __restrict__ g,
                                                  unsigned char* __restrict__ ehat8) {
    const int row  = blockIdx.x * 4 + (threadIdx.x >> 6);
    const int lane = threadIdx.x & 63;
    const float4* src = (const float4*)(embs + (size_t)row * DDIM + lane * 8);
    const float4 a = src[0], b = src[1];
    float ss = a.x*a.x + a.y*a.y + a.z*a.z + a.w*a.w
             + b.x*b.x + b.y*b.y + b.z*b.z + b.w*b.w;
    ss = wave_sum(ss);
    const float norm = sqrtf(ss);
    const float rn = 1.f / norm;
    if (lane == 0) {
        float gg = (norm - 20.f) / sqrtf(10000.f + 1e-3f) * 0.333f;
        gg = fminf(fmaxf(gg, -1.f), 1.f);
        g[row] = gg;
    }
    uint2 pk;
    pk.x = pk4_e4m3(a.x*rn, a.y*rn, a.z*rn, a.w*rn);
    pk.y = pk4_e4m3(b.x*rn, b.y*rn, b.z*rn, b.w*rn);
    *(uint2*)(ehat8 + (size_t)row * DDIM + lane * 8) = pk;
}

// ---- normalized fp8 weight ----
__global__ __launch_bounds__(256) void prep_what8(const float* __restrict__ w,
                                                  unsigned char* __restrict__ what8) {
    const int row  = blockIdx.x * 4 + (threadIdx.x >> 6);
    const int lane = threadIdx.x & 63;
    const float4* src = (const float4*)(w + (size_t)row * DDIM + lane * 8);
    const float4 a = src[0], b = src[1];
    float ss = a.x*a.x + a.y*a.y + a.z*a.z + a.w*a.w
             + b.x*b.x + b.y*b.y + b.z*b.z + b.w*b.w;
    ss = wave_sum(ss);
    const float rn = rsqrtf(ss);
    uint2 pk;
    pk.x = pk4_e4m3(a.x*rn, a.y*rn, a.z*rn, a.w*rn);
    pk.y = pk4_e4m3(b.x*rn, b.y*rn, b.z*rn, b.w*rn);
    *(uint2*)(what8 + (size_t)row * DDIM + lane * 8) = pk;
}

// ==== fp8 tile [128 rows][128 B]; phys 16B-chunk = logical ^ (row&7) ====
// stage: wave writes one 1KB slab (8 rows x 128B) linearly; inverse-swizzled source.
__device__ __forceinline__ void stage8(const unsigned char* __restrict__ src, int grow0,
                                       unsigned char* tile, int kbase, int wv, int lane) {
    const int lr = lane >> 3;                 // row in slab (0..7)
    const int lc = (lane & 7) ^ lr;           // logical chunk at physical slot lane&7
    #pragma unroll
    for (int i = 0; i < 4; ++i) {
        const int s = wv * 4 + i;             // slab 0..15
        const unsigned char* gp = src + (size_t)(grow0 + s * 8 + lr) * DDIM + kbase + lc * 16;
        __builtin_amdgcn_global_load_lds((gvoid_t*)gp, (lvoid_t*)(tile + s * 1024), 16, 0, 0);
    }
}
// fragment: 32 K-bytes at logical chunks 2*(lane>>4), +1, swizzled by row&7 (== lane&7)
__device__ __forceinline__ i32x8 frag8(const unsigned char* tile, int row, int lane) {
    const int c0 = ((lane >> 4) * 2 + 0) ^ (row & 7);
    const int c1 = ((lane >> 4) * 2 + 1) ^ (row & 7);
    const i32x4 lo = *(const i32x4*)(tile + row * 128 + c0 * 16);
    const i32x4 hi = *(const i32x4*)(tile + row * 128 + c1 * 16);
    i32x8 r;
    r[0] = lo[0]; r[1] = lo[1]; r[2] = lo[2]; r[3] = lo[3];
    r[4] = hi[0]; r[5] = hi[1]; r[6] = hi[2]; r[7] = hi[3];
    return r;
}

// ==== 128x128 / BK=128 MX-fp8 GEMM, double-buffered, 2 blocks/CU ====
__global__ __launch_bounds__(256, 2) void gemm128f8(
        const unsigned char* __restrict__ ehat8,   // [1024][512] e4m3
        const unsigned char* __restrict__ what8,   // [WPAD8][512] e4m3
        const int* __restrict__ labels,
        float* __restrict__ psum,                  // [1024][NT8]
        float* __restrict__ dlab)
{
    __shared__ __align__(16) unsigned char Ab[2][128 * 128];  // 2x16 KB
    __shared__ __align__(16) unsigned char Bb[2][128 * 128];  // 2x16 KB
    __shared__ float redbuf[2][128];

    const int tid  = threadIdx.x;
    const int lane = tid & 63;
    const int wv   = tid >> 6;
    const int wr   = wv >> 1;     // 0..1 : 64-row half
    const int wc   = wv & 1;      // 0..1 : 64-col half

    // XCD swizzle: grid 6272 = 8*784 exact; 8 row-tiles of one B panel stay on one XCD
    const int wgid   = ((int)blockIdx.x & 7) * 784 + ((int)blockIdx.x >> 3);
    const int tile_c = wgid >> 3;
    const int tile_r = wgid & 7;
    const int row0   = tile_r * 128;
    const int col0   = tile_c * 128;

    f32x4 acc[4][4];
    #pragma unroll
    for (int m = 0; m < 4; ++m)
        #pragma unroll
        for (int n = 0; n < 4; ++n) acc[m][n] = f32x4{0.f, 0.f, 0.f, 0.f};

    // prologue: stage K-tiles 0 and 1 (16 VMEM issues/wave)
    stage8(ehat8, row0, Ab[0], 0,   wv, lane);
    stage8(what8, col0, Bb[0], 0,   wv, lane);
    stage8(ehat8, row0, Ab[1], 128, wv, lane);
    stage8(what8, col0, Bb[1], 128, wv, lane);
    WAITV(8);                                  // tile 0 landed
    __builtin_amdgcn_s_barrier();

    #pragma unroll
    for (int t = 0; t < 4; ++t) {
        const unsigned char* At = Ab[t & 1];
        const unsigned char* Bt = Bb[t & 1];
        i32x8 aF[4], bF[4];
        #pragma unroll
        for (int m = 0; m < 4; ++m)
            aF[m] = frag8(At, wr * 64 + m * 16 + (lane & 15), lane);
        #pragma unroll
        for (int n = 0; n < 4; ++n)
            bF[n] = frag8(Bt, wc * 64 + n * 16 + (lane & 15), lane);
        asm volatile("s_waitcnt lgkmcnt(0)" ::: "memory");   // reads retired (WAR safety)
        __builtin_amdgcn_sched_barrier(0);
        __builtin_amdgcn_s_barrier();
        if (t < 2) {                           // stage tile t+2 into the buffer just read
            stage8(ehat8, row0, Ab[t & 1], (t + 2) * 128, wv, lane);
            stage8(what8, col0, Bb[t & 1], (t + 2) * 128, wv, lane);
        }
        __builtin_amdgcn_s_setprio(1);
        #pragma unroll
        for (int m = 0; m < 4; ++m)
            #pragma unroll
            for (int n = 0; n < 4; ++n)
                acc[m][n] = __builtin_amdgcn_mfma_scale_f32_16x16x128_f8f6f4(
                                aF[m], bF[n], acc[m][n], 0, 0, 0, 127, 0, 127);
        __builtin_amdgcn_s_setprio(0);
        if (t < 2)      { WAITV(8); }          // tile t+1 landed, t+2 stays in flight
        else if (t == 2){ WAITV(0); }          // last tile landed
        if (t < 3) __builtin_amdgcn_s_barrier();
    }

    // ---- epilogue: clip, label capture, exp-sum ----
    #pragma unroll
    for (int m = 0; m < 4; ++m) {
        #pragma unroll
        for (int j = 0; j < 4; ++j) {
            const int lrow  = wr * 64 + m * 16 + ((lane >> 4) << 2) + j;
            const int r_abs = row0 + lrow;
            const int lab   = labels[r_abs];
            float s = 0.f;
            #pragma unroll
            for (int n = 0; n < 4; ++n) {
                const int c_abs = col0 + wc * 64 + n * 16 + (lane & 15);
                float v = acc[m][n][j];
                v = fminf(fmaxf(v, -0.999f), 0.999f);
                if (c_abs == lab) dlab[r_abs] = v;
                if (c_abs < C_CLS) s += __expf(64.f * v - 64.f);
            }
            #pragma unroll
            for (int msk = 1; msk < 16; msk <<= 1) s += __shfl_xor(s, msk, 64);
            if ((lane & 15) == 0) redbuf[wc][lrow] = s;
        }
    }
    __syncthreads();
    for (int t = tid; t < 128; t += 256)
        psum[(size_t)(row0 + t) * NT8 + tile_c] = redbuf[0][t] + redbuf[1][t];
}

// ==== fallback path (bf16, round-1 verified) ====
__global__ __launch_bounds__(256) void prep_embs(const float* __restrict__ embs,
                                                 float* __restrict__ g,
                                                 unsigned short* __restrict__ ehat) {
    const int row  = blockIdx.x * 4 + (threadIdx.x >> 6);
    const int lane = threadIdx.x & 63;
    const float4* src = (const float4*)(embs + (size_t)row * DDIM + lane * 8);
    const float4 a = src[0], b = src[1];
    float ss = a.x*a.x + a.y*a.y + a.z*a.z + a.w*a.w
             + b.x*b.x + b.y*b.y + b.z*b.z + b.w*b.w;
    ss = wave_sum(ss);
    const float norm = sqrtf(ss);
    const float rn = 1.f / norm;
    if (lane == 0) {
        float gg = (norm - 20.f) / sqrtf(10000.f + 1e-3f) * 0.333f;
        gg = fminf(fmaxf(gg, -1.f), 1.f);
        g[row] = gg;
    }
    uint4 pk;
    pk.x = f2bf(a.x*rn) | (f2bf(a.y*rn) << 16);
    pk.y = f2bf(a.z*rn) | (f2bf(a.w*rn) << 16);
    pk.z = f2bf(b.x*rn) | (f2bf(b.y*rn) << 16);
    pk.w = f2bf(b.z*rn) | (f2bf(b.w*rn) << 16);
    *(uint4*)(ehat + (size_t)row * DDIM + lane * 8) = pk;
}

__global__ __launch_bounds__(256) void prep_wnorm(const float* __restrict__ w,
                                                  float* __restrict__ rnormw) {
    const int row  = blockIdx.x * 4 + (threadIdx.x >> 6);
    const int lane = threadIdx.x & 63;
    const float4* src = (const float4*)(w + (size_t)row * DDIM + lane * 8);
    const float4 a = src[0], b = src[1];
    float ss = a.x*a.x + a.y*a.y + a.z*a.z + a.w*a.w
             + b.x*b.x + b.y*b.y + b.z*b.z + b.w*b.w;
    ss = wave_sum(ss);
    if (lane == 0) rnormw[row] = 1.f / sqrtf(ss);
}

__global__ __launch_bounds__(256, 2) void gemm_fused_fb(
        const unsigned short* __restrict__ ehat,
        const float* __restrict__ weight,
        const float* __restrict__ rnormw,
        const int* __restrict__ labels,
        float* __restrict__ psum,
        float* __restrict__ dlab)
{
    constexpr int BM = 128, BN = 128, BK = 32;
    __shared__ __align__(16) unsigned short Asf[BM * BK];
    __shared__ __align__(16) unsigned short Bsf[BN * BK];
    __shared__ float redbuf[2][BM];

    const int bid    = blockIdx.x;
    const int tile_c = bid >> 3;
    const int tile_r = bid & 7;
    const int row0   = tile_r * BM;
    const int col0   = tile_c * BN;

    const int tid  = threadIdx.x;
    const int lane = tid & 63;
    const int wv   = tid >> 6;
    const int wr   = wv >> 1;
    const int wc   = wv & 1;

    f32x4 acc[4][4];
    #pragma unroll
    for (int m = 0; m < 4; ++m)
        #pragma unroll
        for (int n = 0; n < 4; ++n) acc[m][n] = f32x4{0.f, 0.f, 0.f, 0.f};

    const int kq    = tid & 7;
    const int brow0 = tid >> 3;
    int   cidx[4];
    float rnv[4];
    #pragma unroll
    for (int p = 0; p < 4; ++p) {
        int c = col0 + p * 32 + brow0;
        c = c < C_CLS ? c : C_CLS - 1;
        cidx[p] = c;
        rnv[p]  = rnormw[c];
    }

    for (int kt = 0; kt < DDIM / BK; ++kt) {
        const int kbase = kt * BK;
        #pragma unroll
        for (int call = 0; call < 2; ++call) {
            const int chunk = call * 256 + tid;
            const uint4 d = *(const uint4*)(ehat + (size_t)(row0 + (chunk >> 2)) * DDIM
                                            + kbase + (chunk & 3) * 8);
            *(uint4*)(Asf + chunk * 8) = d;
        }
        #pragma unroll
        for (int p = 0; p < 4; ++p) {
            const float4 wd = *(const float4*)(weight + (size_t)cidx[p] * DDIM + kbase + kq * 4);
            const float r = rnv[p];
            const unsigned int lo = f2bf(wd.x * r) | (f2bf(wd.y * r) << 16);
            const unsigned int hi = f2bf(wd.z * r) | (f2bf(wd.w * r) << 16);
            *(uint2*)(Bsf + (p * 32 + brow0) * BK + kq * 4) = make_uint2(lo, hi);
        }
        __syncthreads();
        bf16x8 af[4], bfr[4];
        const int lr  = lane & 15;
        const int lko = (lane >> 4) * 8;
        #pragma unroll
        for (int m = 0; m < 4; ++m)
            af[m] = *(const bf16x8*)(Asf + (wr * 64 + m * 16 + lr) * BK + lko);
        #pragma unroll
        for (int n = 0; n < 4; ++n)
            bfr[n] = *(const bf16x8*)(Bsf + (wc * 64 + n * 16 + lr) * BK + lko);
        #pragma unroll
        for (int m = 0; m < 4; ++m)
            #pragma unroll
            for (int n = 0; n < 4; ++n)
                acc[m][n] = __builtin_amdgcn_mfma_f32_16x16x32_bf16(af[m], bfr[n], acc[m][n], 0, 0, 0);
        __syncthreads();
    }

    #pragma unroll
    for (int m = 0; m < 4; ++m) {
        #pragma unroll
        for (int j = 0; j < 4; ++j) {
            const int lrow  = wr * 64 + m * 16 + ((lane >> 4) << 2) + j;
            const int r_abs = row0 + lrow;
            const int lab   = labels[r_abs];
            float s = 0.f;
            #pragma unroll
            for (int n = 0; n < 4; ++n) {
                const int c_abs = col0 + wc * 64 + n * 16 + (lane & 15);
                float v = acc[m][n][j];
                v = fminf(fmaxf(v, -0.999f), 0.999f);
                if (c_abs == lab) dlab[r_abs] = v;
                if (c_abs < C_CLS) s += __expf(64.f * v - 64.f);
            }
            #pragma unroll
            for (int msk = 1; msk < 16; msk <<= 1) s += __shfl_xor(s, msk, 64);
            if ((lane & 15) == 0) redbuf[wc][lrow] = s;
        }
    }
    __syncthreads();
    for (int t = tid; t < BM; t += 256)
        psum[(size_t)(row0 + t) * NT_FB + tile_c] = redbuf[0][t] + redbuf[1][t];
}

// ---- per-row combine + margin correction at label ----
__global__ __launch_bounds__(256) void reduce_rows(const float* __restrict__ psum,
                                                   const float* __restrict__ dlab,
                                                   const float* __restrict__ g,
                                                   float* __restrict__ losses, int nt) {
    const int row  = blockIdx.x * 4 + (threadIdx.x >> 6);
    const int lane = threadIdx.x & 63;
    const float* p = psum + (size_t)row * nt;
    float s = 0.f;
    for (int t = lane; t < nt; t += 64) s += p[t];
    s = wave_sum(s);
    if (lane == 0) {
        const float v  = dlab[row];
        const float gg = g[row];
        float th = acosf(v) - MARG * gg;
        th = fminf(fmaxf(th, 0.f), 3.14159265358979323846f);
        const float vm = cosf(th) - (1.f + MARG) * gg;
        s = s - __expf(64.f * v - 64.f) + __expf(64.f * vm - 64.f);
        losses[row] = 64.f + logf(s) - 64.f * vm;
    }
}

__global__ __launch_bounds__(256) void final_mean(const float* __restrict__ losses,
                                                  float* __restrict__ out) {
    const int tid = threadIdx.x;
    float s = 0.f;
    #pragma unroll
    for (int i = 0; i < 4; ++i) s += losses[tid + i * 256];
    s = wave_sum(s);
    __shared__ float red[4];
    if ((tid & 63) == 0) red[tid >> 6] = s;
    __syncthreads();
    if (tid == 0) out[0] = (red[0] + red[1] + red[2] + red[3]) * (1.f / 1024.f);
}

extern "C" void kernel_launch(void* const* d_in, const int* in_sizes, int n_in,
                              void* d_out, int out_size, void* d_ws, size_t ws_size,
                              hipStream_t stream) {
    const float* embs   = (const float*)d_in[0];
    const float* weight = (const float*)d_in[1];
    const int*   labels = (const int*)d_in[2];
    float* out = (float*)d_out;
    unsigned char* wsb = (unsigned char*)d_ws;

    // main-path layout (bytes)
    const size_t WHAT8_B = (size_t)WPAD8 * DDIM;          // 51,380,224
    const size_t EHAT8_B = (size_t)N_ROWS * DDIM;         // 524,288
    const size_t PSUM_B  = (size_t)N_ROWS * NT8 * 4;      // 3,211,264
    const size_t NEED_B  = WHAT8_B + EHAT8_B + PSUM_B + 3 * 4096;

    if (ws_size >= NEED_B) {
        unsigned char* what8 = wsb;
        unsigned char* ehat8 = wsb + WHAT8_B;
        float* psum   = (float*)(wsb + WHAT8_B + EHAT8_B);
        float* gbuf   = psum + (size_t)N_ROWS * NT8;
        float* dlab   = gbuf + 1024;
        float* losses = dlab + 1024;

        prep_embs8<<<N_ROWS / 4, 256, 0, stream>>>(embs, gbuf, ehat8);
        prep_what8<<<C_CLS / 4, 256, 0, stream>>>(weight, what8);
        gemm128f8<<<NT8 * 8, 256, 0, stream>>>(ehat8, what8, labels, psum, dlab);
        reduce_rows<<<N_ROWS / 4, 256, 0, stream>>>(psum, dlab, gbuf, losses, NT8);
        final_mean<<<1, 256, 0, stream>>>(losses, out);
    } else {
        float* ws = (float*)d_ws;
        float* rnormw = ws + 0;
        float* gbuf   = ws + 100352;
        float* dlab   = ws + 101376;
        float* losses = ws + 102400;
        unsigned short* ehat = (unsigned short*)(ws + 103424);
        float* psum   = ws + 103424 + 262144;

        prep_embs <<<N_ROWS / 4, 256, 0, stream>>>(embs, gbuf, ehat);
        prep_wnorm<<<C_CLS / 4, 256, 0, stream>>>(weight, rnormw);
        gemm_fused_fb<<<NT_FB * 8, 256, 0, stream>>>(ehat, weight, rnormw, labels, psum, dlab);
        reduce_rows<<<N_ROWS / 4, 256, 0, stream>>>(psum, dlab, gbuf, losses, NT_FB);
        final_mean<<<1, 256, 0, stream>>>(losses, out);
    }
}